// Round 1
// baseline (233.387 us; speedup 1.0000x reference)
//
#include <hip/hip_runtime.h>
#include <math.h>

#define NRES 4096
#define CONTACT_ROWS 8   // rows per block -> 512 blocks, 48KB LDS => ~3 blk/CU cap, 2 resident

// ---- wave (64-lane) reduce, lane0 atomically adds to dst ----
__device__ __forceinline__ void wave_reduce_atomic(float v, float* dst) {
#pragma unroll
    for (int off = 32; off > 0; off >>= 1) v += __shfl_down(v, off, 64);
    if ((threadIdx.x & 63) == 0) atomicAdd(dst, v);
}

// ---- bond + hydrogen-bond terms (O(n), tiny) ----
__global__ __launch_bounds__(256) void bond_hb_kernel(const float* __restrict__ ca,
                                                      float* __restrict__ acc, int n) {
    int i = blockIdx.x * 256 + threadIdx.x;
    float bond = 0.f, hb = 0.f;

    if (i < n - 1) {
        float dx = ca[3*(i+1)+0] - ca[3*i+0];
        float dy = ca[3*(i+1)+1] - ca[3*i+1];
        float dz = ca[3*(i+1)+2] - ca[3*i+2];
        float d  = sqrtf(dx*dx + dy*dy + dz*dz);
        float t  = d - 3.8f;
        bond = t * t;
    }

    // hb pairs (o[i], n_atom[i+off]) exist for off in [2,5], i+off < n  =>  i < n-2
    if (i < n - 2) {
        float cax = ca[3*i+0], cay = ca[3*i+1], caz = ca[3*i+2];
        // unit[i] = (ca[i+1]-ca[i]) / (|..| + 1e-8)
        float vx = ca[3*(i+1)+0] - cax;
        float vy = ca[3*(i+1)+1] - cay;
        float vz = ca[3*(i+1)+2] - caz;
        float inv = 1.f / (sqrtf(vx*vx + vy*vy + vz*vz) + 1e-8f);
        float ux = vx*inv, uy = vy*inv, uz = vz*inv;

        float upx, upy, upz;   // unit[i-1] (or unit[0] for i==0)
        if (i == 0) { upx = ux; upy = uy; upz = uz; }
        else {
            float wx = cax - ca[3*(i-1)+0];
            float wy = cay - ca[3*(i-1)+1];
            float wz = caz - ca[3*(i-1)+2];
            float inv2 = 1.f / (sqrtf(wx*wx + wy*wy + wz*wz) + 1e-8f);
            upx = wx*inv2; upy = wy*inv2; upz = wz*inv2;
        }

        // vec_c = c[i]-ca[i] = 0.38*unit[i];  vec_n = n[i]-ca[i] = -0.38*unit[i-1]
        float vcx = 0.38f*ux,  vcy = 0.38f*uy,  vcz = 0.38f*uz;
        float vnx = -0.38f*upx, vny = -0.38f*upy, vnz = -0.38f*upz;
        // perp = cross(vec_c, vec_n)
        float px = vcy*vnz - vcz*vny;
        float py = vcz*vnx - vcx*vnz;
        float pz = vcx*vny - vcy*vnx;
        float pn = sqrtf(px*px + py*py + pz*pz);
        if (pn > 1e-6f) {
            float ipn = 1.f / fmaxf(pn, 1e-12f);
            px *= ipn; py *= ipn; pz *= ipn;
        }
        float ox = cax + vcx + 1.24f*px;
        float oy = cay + vcy + 1.24f*py;
        float oz = caz + vcz + 1.24f*pz;

#pragma unroll
        for (int off = 2; off <= 5; ++off) {
            int j = i + off;
            if (j < n) {
                float cjx = ca[3*j+0], cjy = ca[3*j+1], cjz = ca[3*j+2];
                float qx = cjx - ca[3*(j-1)+0];
                float qy = cjy - ca[3*(j-1)+1];
                float qz = cjz - ca[3*(j-1)+2];
                float invq = 1.f / (sqrtf(qx*qx + qy*qy + qz*qz) + 1e-8f);
                float njx = cjx - 0.38f*qx*invq;
                float njy = cjy - 0.38f*qy*invq;
                float njz = cjz - 0.38f*qz*invq;
                float ddx = ox - njx, ddy = oy - njy, ddz = oz - njz;
                float d = sqrtf(ddx*ddx + ddy*ddy + ddz*ddz);
                if (d > 2.5f && d < 3.5f) {
                    float z = (d - 2.95f) * (1.0f / 0.3f);
                    hb -= 0.5f * expf(-z*z);
                }
            }
        }
    }

    wave_reduce_atomic(bond, acc + 0);
    wave_reduce_atomic(hb,   acc + 3);
}

// ---- clash term over 500K random pairs ----
__global__ __launch_bounds__(256) void clash_kernel(const float* __restrict__ ca,
                                                    const int* __restrict__ pairs,
                                                    float* __restrict__ acc, int npairs) {
    int p = blockIdx.x * 256 + threadIdx.x;
    float v = 0.f;
    if (p < npairs) {
        int i0 = pairs[2*p + 0];
        int i1 = pairs[2*p + 1];
        float dx = ca[3*i0+0] - ca[3*i1+0];
        float dy = ca[3*i0+1] - ca[3*i1+1];
        float dz = ca[3*i0+2] - ca[3*i1+2];
        float d  = sqrtf(fmaxf(dx*dx + dy*dy + dz*dz, 1e-12f));
        float r  = fmaxf(3.2f - d, 0.f);
        v = r * r;
    }
    wave_reduce_atomic(v, acc + 1);
}

// ---- contact term: full NxN, K streamed once, ca staged in LDS ----
__global__ __launch_bounds__(256) void contact_kernel(const float* __restrict__ ca,
                                                      const float* __restrict__ K,
                                                      float* __restrict__ acc, int n) {
    __shared__ float sx[NRES], sy[NRES], sz[NRES];   // 48 KB
    int tid = threadIdx.x;
    for (int j = tid; j < n; j += 256) {
        sx[j] = ca[3*j+0];
        sy[j] = ca[3*j+1];
        sz[j] = ca[3*j+2];
    }
    __syncthreads();

    int row0 = blockIdx.x * CONTACT_ROWS;
    float lsum = 0.f;
    int nq = n >> 2;   // float4 groups per row

#pragma unroll
    for (int r = 0; r < CONTACT_ROWS; ++r) {
        int i = row0 + r;
        float xi = sx[i], yi = sy[i], zi = sz[i];
        const float4* Krow4 = (const float4*)(K + (size_t)i * n);
        for (int j4 = tid; j4 < nq; j4 += 256) {
            float4 kv = Krow4[j4];
            int j = j4 << 2;
            float4 cx = *(const float4*)&sx[j];
            float4 cy = *(const float4*)&sy[j];
            float4 cz = *(const float4*)&sz[j];

            float dx, dy, dz, sq, D, t;
            dx = xi - cx.x; dy = yi - cy.x; dz = zi - cz.x;
            sq = dx*dx + dy*dy + dz*dz;
            D  = sqrtf(fmaxf(sq, 1e-12f));
            t  = D - 8.0f*(1.0f - kv.x);  lsum += t*t;

            dx = xi - cx.y; dy = yi - cy.y; dz = zi - cz.y;
            sq = dx*dx + dy*dy + dz*dz;
            D  = sqrtf(fmaxf(sq, 1e-12f));
            t  = D - 8.0f*(1.0f - kv.y);  lsum += t*t;

            dx = xi - cx.z; dy = yi - cy.z; dz = zi - cz.z;
            sq = dx*dx + dy*dy + dz*dz;
            D  = sqrtf(fmaxf(sq, 1e-12f));
            t  = D - 8.0f*(1.0f - kv.z);  lsum += t*t;

            dx = xi - cx.w; dy = yi - cy.w; dz = zi - cz.w;
            sq = dx*dx + dy*dy + dz*dz;
            D  = sqrtf(fmaxf(sq, 1e-12f));
            t  = D - 8.0f*(1.0f - kv.w);  lsum += t*t;
        }
    }
    wave_reduce_atomic(lsum, acc + 2);
}

// ---- combine ----
__global__ void finalize_kernel(const float* __restrict__ acc, float* __restrict__ out,
                                int n, int npairs) {
    float e_bond    = 30.f * acc[0] / (float)(n - 1);
    float e_clash   = 50.f * acc[1] / (float)npairs;
    float inv_nn    = 1.f / ((float)n * (float)n);
    float e_contact = 5.f * acc[2] * inv_nn;
    float e_hb      = 4.f * acc[3] * inv_nn;
    out[0] = e_bond + e_clash + e_contact + e_hb;
}

extern "C" void kernel_launch(void* const* d_in, const int* in_sizes, int n_in,
                              void* d_out, int out_size, void* d_ws, size_t ws_size,
                              hipStream_t stream) {
    const float* ca    = (const float*)d_in[0];
    const float* K     = (const float*)d_in[1];
    const int*   pairs = (const int*)d_in[2];   // jnp.int64 downgrades to int32 (x64 off)
    float* out = (float*)d_out;
    float* acc = (float*)d_ws;                  // acc[0]=bond acc[1]=clash acc[2]=contact acc[3]=hb

    int n      = in_sizes[0] / 3;               // 4096
    int npairs = in_sizes[2] / 2;               // 500000

    hipMemsetAsync(acc, 0, 4 * sizeof(float), stream);

    bond_hb_kernel<<<(n + 255) / 256, 256, 0, stream>>>(ca, acc, n);
    clash_kernel<<<(npairs + 255) / 256, 256, 0, stream>>>(ca, pairs, acc, npairs);
    contact_kernel<<<n / CONTACT_ROWS, 256, 0, stream>>>(ca, K, acc, n);
    finalize_kernel<<<1, 1, 0, stream>>>(acc, out, n, npairs);
}

// Round 2
// 116.402 us; speedup vs baseline: 2.0050x; 2.0050x over previous
//
#include <hip/hip_runtime.h>
#include <math.h>

#define NRES 4096
#define CONTACT_ROWS 8
#define CONTACT_BLOCKS 512   // 512 * 8 rows = 4096
#define CLASH_BLOCKS   256
#define BOND_BLOCKS    16    // 16 * 256 = 4096 threads

// ---- block (256-thread) reduce -> ONE atomic per block ----
__device__ __forceinline__ void block_reduce_atomic(float v, float* red, float* dst) {
#pragma unroll
    for (int off = 32; off > 0; off >>= 1) v += __shfl_down(v, off, 64);
    if ((threadIdx.x & 63) == 0) red[threadIdx.x >> 6] = v;
    __syncthreads();
    if (threadIdx.x == 0) atomicAdd(dst, red[0] + red[1] + red[2] + red[3]);
    __syncthreads();   // allow red[] reuse by a second call
}

// ---- one fused kernel, blocks partitioned by role so phases overlap ----
// acc[0]=bond acc[1]=clash acc[2]=contact acc[3]=hb
__global__ __launch_bounds__(256) void energy_kernel(const float* __restrict__ ca,
                                                     const float* __restrict__ K,
                                                     const int* __restrict__ pairs,
                                                     float* __restrict__ acc,
                                                     int n, int npairs) {
    __shared__ float sx[NRES], sy[NRES], sz[NRES];   // 48 KB -> 3 blocks/CU cap
    __shared__ float red[4];
    int tid = threadIdx.x;
    for (int j = tid; j < n; j += 256) {
        sx[j] = ca[3*j+0];
        sy[j] = ca[3*j+1];
        sz[j] = ca[3*j+2];
    }
    __syncthreads();

    int b = blockIdx.x;

    if (b < CONTACT_BLOCKS) {
        // ---------------- contact: stream K once, HBM-bound ----------------
        int row0 = b * CONTACT_ROWS;
        float lsum = 0.f;
        int nq = n >> 2;
#pragma unroll
        for (int r = 0; r < CONTACT_ROWS; ++r) {
            int i = row0 + r;
            float xi = sx[i], yi = sy[i], zi = sz[i];
            const float4* Krow4 = (const float4*)(K + (size_t)i * n);
            for (int j4 = tid; j4 < nq; j4 += 256) {
                float4 kv = Krow4[j4];
                int j = j4 << 2;
                float4 cx = *(const float4*)&sx[j];
                float4 cy = *(const float4*)&sy[j];
                float4 cz = *(const float4*)&sz[j];

                float dx, dy, dz, sq, D, t;
                dx = xi - cx.x; dy = yi - cy.x; dz = zi - cz.x;
                sq = dx*dx + dy*dy + dz*dz;
                D  = sqrtf(fmaxf(sq, 1e-12f));
                t  = D - 8.0f*(1.0f - kv.x);  lsum += t*t;

                dx = xi - cx.y; dy = yi - cy.y; dz = zi - cz.y;
                sq = dx*dx + dy*dy + dz*dz;
                D  = sqrtf(fmaxf(sq, 1e-12f));
                t  = D - 8.0f*(1.0f - kv.y);  lsum += t*t;

                dx = xi - cx.z; dy = yi - cy.z; dz = zi - cz.z;
                sq = dx*dx + dy*dy + dz*dz;
                D  = sqrtf(fmaxf(sq, 1e-12f));
                t  = D - 8.0f*(1.0f - kv.z);  lsum += t*t;

                dx = xi - cx.w; dy = yi - cy.w; dz = zi - cz.w;
                sq = dx*dx + dy*dy + dz*dz;
                D  = sqrtf(fmaxf(sq, 1e-12f));
                t  = D - 8.0f*(1.0f - kv.w);  lsum += t*t;
            }
        }
        block_reduce_atomic(lsum, red, acc + 2);

    } else if (b < CONTACT_BLOCKS + CLASH_BLOCKS) {
        // ---------------- clash: grid-stride gathers from LDS ----------------
        int cb = b - CONTACT_BLOCKS;
        float v = 0.f;
        for (int p = cb * 256 + tid; p < npairs; p += CLASH_BLOCKS * 256) {
            int i0 = pairs[2*p + 0];
            int i1 = pairs[2*p + 1];
            float dx = sx[i0] - sx[i1];
            float dy = sy[i0] - sy[i1];
            float dz = sz[i0] - sz[i1];
            float d  = sqrtf(fmaxf(dx*dx + dy*dy + dz*dz, 1e-12f));
            float r  = fmaxf(3.2f - d, 0.f);
            v += r * r;
        }
        block_reduce_atomic(v, red, acc + 1);

    } else {
        // ---------------- bond + hydrogen bond (O(n)) ----------------
        int ib = b - CONTACT_BLOCKS - CLASH_BLOCKS;
        int i = ib * 256 + tid;
        float bond = 0.f, hb = 0.f;

        if (i < n - 1) {
            float dx = sx[i+1] - sx[i];
            float dy = sy[i+1] - sy[i];
            float dz = sz[i+1] - sz[i];
            float d  = sqrtf(dx*dx + dy*dy + dz*dz);
            float t  = d - 3.8f;
            bond = t * t;
        }

        if (i < n - 2) {
            float cax = sx[i], cay = sy[i], caz = sz[i];
            float vx = sx[i+1] - cax, vy = sy[i+1] - cay, vz = sz[i+1] - caz;
            float inv = 1.f / (sqrtf(vx*vx + vy*vy + vz*vz) + 1e-8f);
            float ux = vx*inv, uy = vy*inv, uz = vz*inv;

            float upx, upy, upz;
            if (i == 0) { upx = ux; upy = uy; upz = uz; }
            else {
                float wx = cax - sx[i-1], wy = cay - sy[i-1], wz = caz - sz[i-1];
                float inv2 = 1.f / (sqrtf(wx*wx + wy*wy + wz*wz) + 1e-8f);
                upx = wx*inv2; upy = wy*inv2; upz = wz*inv2;
            }

            float vcx = 0.38f*ux,  vcy = 0.38f*uy,  vcz = 0.38f*uz;
            float vnx = -0.38f*upx, vny = -0.38f*upy, vnz = -0.38f*upz;
            float px = vcy*vnz - vcz*vny;
            float py = vcz*vnx - vcx*vnz;
            float pz = vcx*vny - vcy*vnx;
            float pn = sqrtf(px*px + py*py + pz*pz);
            if (pn > 1e-6f) {
                float ipn = 1.f / fmaxf(pn, 1e-12f);
                px *= ipn; py *= ipn; pz *= ipn;
            }
            float ox = cax + vcx + 1.24f*px;
            float oy = cay + vcy + 1.24f*py;
            float oz = caz + vcz + 1.24f*pz;

#pragma unroll
            for (int off = 2; off <= 5; ++off) {
                int j = i + off;
                if (j < n) {
                    float cjx = sx[j], cjy = sy[j], cjz = sz[j];
                    float qx = cjx - sx[j-1], qy = cjy - sy[j-1], qz = cjz - sz[j-1];
                    float invq = 1.f / (sqrtf(qx*qx + qy*qy + qz*qz) + 1e-8f);
                    float njx = cjx - 0.38f*qx*invq;
                    float njy = cjy - 0.38f*qy*invq;
                    float njz = cjz - 0.38f*qz*invq;
                    float ddx = ox - njx, ddy = oy - njy, ddz = oz - njz;
                    float d = sqrtf(ddx*ddx + ddy*ddy + ddz*ddz);
                    if (d > 2.5f && d < 3.5f) {
                        float z = (d - 2.95f) * (1.0f / 0.3f);
                        hb -= 0.5f * expf(-z*z);
                    }
                }
            }
        }

        block_reduce_atomic(bond, red, acc + 0);
        block_reduce_atomic(hb,   red, acc + 3);
    }
}

// ---- combine ----
__global__ void finalize_kernel(const float* __restrict__ acc, float* __restrict__ out,
                                int n, int npairs) {
    float e_bond    = 30.f * acc[0] / (float)(n - 1);
    float e_clash   = 50.f * acc[1] / (float)npairs;
    float inv_nn    = 1.f / ((float)n * (float)n);
    float e_contact = 5.f * acc[2] * inv_nn;
    float e_hb      = 4.f * acc[3] * inv_nn;
    out[0] = e_bond + e_clash + e_contact + e_hb;
}

extern "C" void kernel_launch(void* const* d_in, const int* in_sizes, int n_in,
                              void* d_out, int out_size, void* d_ws, size_t ws_size,
                              hipStream_t stream) {
    const float* ca    = (const float*)d_in[0];
    const float* K     = (const float*)d_in[1];
    const int*   pairs = (const int*)d_in[2];   // int32 on device (x64 disabled)
    float* out = (float*)d_out;
    float* acc = (float*)d_ws;

    int n      = in_sizes[0] / 3;               // 4096
    int npairs = in_sizes[2] / 2;               // 500000

    hipMemsetAsync(acc, 0, 4 * sizeof(float), stream);

    int grid = CONTACT_BLOCKS + CLASH_BLOCKS + BOND_BLOCKS;
    energy_kernel<<<grid, 256, 0, stream>>>(ca, K, pairs, acc, n, npairs);
    finalize_kernel<<<1, 1, 0, stream>>>(acc, out, n, npairs);
}

// Round 3
// 111.062 us; speedup vs baseline: 2.1014x; 1.0481x over previous
//
#include <hip/hip_runtime.h>
#include <math.h>

#define NRES   4096
#define NBLK   512            // contact: 512 blocks x 8 rows = 4096 rows
#define ROWS   8
#define NQ     (NRES / 4)     // 1024 float4 per K row
#define CHUNKS (NQ / 256)     // 4 j4-chunks per row per thread

__device__ __forceinline__ float wave_sum(float v) {
#pragma unroll
    for (int off = 32; off > 0; off >>= 1) v += __shfl_down(v, off, 64);
    return v;
}

// Every block: stage ca -> LDS, contact (8 exact rows), clash (grid-stride),
// bond+hb (8 residues). Partials to d_ws (no atomics). partial[b] =
// {bond, clash, contact, hb}.
__global__ __launch_bounds__(256) void energy_kernel(const float* __restrict__ ca,
                                                     const float* __restrict__ K,
                                                     const int* __restrict__ pairs,
                                                     float4* __restrict__ partial,
                                                     int npairs) {
    __shared__ float sx[NRES], sy[NRES], sz[NRES];   // 48 KB
    __shared__ float red[4][4];                      // [wave][term]
    const int tid = threadIdx.x;
    const int b   = blockIdx.x;

    for (int j = tid; j < NRES; j += 256) {
        sx[j] = ca[3*j+0];
        sy[j] = ca[3*j+1];
        sz[j] = ca[3*j+2];
    }
    __syncthreads();

    // ---------------- contact: 8 rows, K streamed with 8 loads in flight ----------------
    const int row0 = b * ROWS;
    float xi[ROWS], yi[ROWS], zi[ROWS];
#pragma unroll
    for (int r = 0; r < ROWS; ++r) {
        xi[r] = sx[row0 + r]; yi[r] = sy[row0 + r]; zi[r] = sz[row0 + r];
    }

    float contact = 0.f;
    const float4* Kp = (const float4*)(K + (size_t)row0 * NRES);
#pragma unroll
    for (int k = 0; k < CHUNKS; ++k) {
        const int j4 = tid + (k << 8);
        float4 kv[ROWS];
#pragma unroll
        for (int r = 0; r < ROWS; ++r) kv[r] = Kp[(size_t)r * NQ + j4];   // 8 outstanding
        const int j = j4 << 2;
        const float4 cx = *(const float4*)&sx[j];
        const float4 cy = *(const float4*)&sy[j];
        const float4 cz = *(const float4*)&sz[j];
#pragma unroll
        for (int r = 0; r < ROWS; ++r) {
            float dx, dy, dz, sq, D, t;
            dx = xi[r]-cx.x; dy = yi[r]-cy.x; dz = zi[r]-cz.x;
            sq = fmaf(dx, dx, fmaf(dy, dy, dz*dz));
            D  = sqrtf(fmaxf(sq, 1e-12f));
            t  = fmaf(8.f, kv[r].x, D - 8.f);            // D - 8(1-k)
            contact = fmaf(t, t, contact);

            dx = xi[r]-cx.y; dy = yi[r]-cy.y; dz = zi[r]-cz.y;
            sq = fmaf(dx, dx, fmaf(dy, dy, dz*dz));
            D  = sqrtf(fmaxf(sq, 1e-12f));
            t  = fmaf(8.f, kv[r].y, D - 8.f);
            contact = fmaf(t, t, contact);

            dx = xi[r]-cx.z; dy = yi[r]-cy.z; dz = zi[r]-cz.z;
            sq = fmaf(dx, dx, fmaf(dy, dy, dz*dz));
            D  = sqrtf(fmaxf(sq, 1e-12f));
            t  = fmaf(8.f, kv[r].z, D - 8.f);
            contact = fmaf(t, t, contact);

            dx = xi[r]-cx.w; dy = yi[r]-cy.w; dz = zi[r]-cz.w;
            sq = fmaf(dx, dx, fmaf(dy, dy, dz*dz));
            D  = sqrtf(fmaxf(sq, 1e-12f));
            t  = fmaf(8.f, kv[r].w, D - 8.f);
            contact = fmaf(t, t, contact);
        }
    }

    // ---------------- clash: grid-stride over pairs, gathers from LDS ----------------
    float clash = 0.f;
    for (int p = b * 256 + tid; p < npairs; p += NBLK * 256) {
        int2 pr = ((const int2*)pairs)[p];
        float dx = sx[pr.x] - sx[pr.y];
        float dy = sy[pr.x] - sy[pr.y];
        float dz = sz[pr.x] - sz[pr.y];
        float d  = sqrtf(fmaxf(fmaf(dx, dx, fmaf(dy, dy, dz*dz)), 1e-12f));
        float r  = fmaxf(3.2f - d, 0.f);
        clash = fmaf(r, r, clash);
    }

    // ---------------- bond + hb: 8 residues per block (threads 0..7) ----------------
    float bond = 0.f, hb = 0.f;
    if (tid < ROWS) {
        const int i = row0 + tid;
        const int n = NRES;

        if (i < n - 1) {
            float dx = sx[i+1]-sx[i], dy = sy[i+1]-sy[i], dz = sz[i+1]-sz[i];
            float d  = sqrtf(fmaf(dx, dx, fmaf(dy, dy, dz*dz)));
            float t  = d - 3.8f;
            bond = t * t;
        }

        if (i < n - 2) {
            float cax = sx[i], cay = sy[i], caz = sz[i];
            float vx = sx[i+1]-cax, vy = sy[i+1]-cay, vz = sz[i+1]-caz;
            float inv = 1.f / (sqrtf(vx*vx + vy*vy + vz*vz) + 1e-8f);
            float ux = vx*inv, uy = vy*inv, uz = vz*inv;

            float upx, upy, upz;
            if (i == 0) { upx = ux; upy = uy; upz = uz; }
            else {
                float wx = cax-sx[i-1], wy = cay-sy[i-1], wz = caz-sz[i-1];
                float inv2 = 1.f / (sqrtf(wx*wx + wy*wy + wz*wz) + 1e-8f);
                upx = wx*inv2; upy = wy*inv2; upz = wz*inv2;
            }

            float vcx = 0.38f*ux,  vcy = 0.38f*uy,  vcz = 0.38f*uz;
            float vnx = -0.38f*upx, vny = -0.38f*upy, vnz = -0.38f*upz;
            float px = vcy*vnz - vcz*vny;
            float py = vcz*vnx - vcx*vnz;
            float pz = vcx*vny - vcy*vnx;
            float pn = sqrtf(px*px + py*py + pz*pz);
            if (pn > 1e-6f) {
                float ipn = 1.f / fmaxf(pn, 1e-12f);
                px *= ipn; py *= ipn; pz *= ipn;
            }
            float ox = cax + vcx + 1.24f*px;
            float oy = cay + vcy + 1.24f*py;
            float oz = caz + vcz + 1.24f*pz;

#pragma unroll
            for (int off = 2; off <= 5; ++off) {
                int jj = i + off;
                if (jj < n) {
                    float cjx = sx[jj], cjy = sy[jj], cjz = sz[jj];
                    float qx = cjx-sx[jj-1], qy = cjy-sy[jj-1], qz = cjz-sz[jj-1];
                    float invq = 1.f / (sqrtf(qx*qx + qy*qy + qz*qz) + 1e-8f);
                    float njx = cjx - 0.38f*qx*invq;
                    float njy = cjy - 0.38f*qy*invq;
                    float njz = cjz - 0.38f*qz*invq;
                    float ddx = ox-njx, ddy = oy-njy, ddz = oz-njz;
                    float d = sqrtf(ddx*ddx + ddy*ddy + ddz*ddz);
                    if (d > 2.5f && d < 3.5f) {
                        float z = (d - 2.95f) * (1.0f / 0.3f);
                        hb -= 0.5f * expf(-z*z);
                    }
                }
            }
        }
    }

    // ---------------- block reduce (no atomics), partial[b] = 4 terms ----------------
    float vb = wave_sum(bond);
    float vc = wave_sum(clash);
    float vk = wave_sum(contact);
    float vh = wave_sum(hb);
    const int wave = tid >> 6;
    if ((tid & 63) == 0) {
        red[wave][0] = vb; red[wave][1] = vc; red[wave][2] = vk; red[wave][3] = vh;
    }
    __syncthreads();
    if (tid == 0) {
        float4 out;
        out.x = red[0][0] + red[1][0] + red[2][0] + red[3][0];
        out.y = red[0][1] + red[1][1] + red[2][1] + red[3][1];
        out.z = red[0][2] + red[1][2] + red[2][2] + red[3][2];
        out.w = red[0][3] + red[1][3] + red[2][3] + red[3][3];
        partial[b] = out;
    }
}

// ---- reduce 512 partials, apply weights ----
__global__ __launch_bounds__(256) void finalize_kernel(const float4* __restrict__ partial,
                                                       float* __restrict__ out,
                                                       int n, int npairs) {
    __shared__ float red[4][4];
    const int tid = threadIdx.x;
    float4 a = partial[tid];
    float4 c = partial[tid + 256];
    float vb = a.x + c.x, vc = a.y + c.y, vk = a.z + c.z, vh = a.w + c.w;
    vb = wave_sum(vb); vc = wave_sum(vc); vk = wave_sum(vk); vh = wave_sum(vh);
    const int wave = tid >> 6;
    if ((tid & 63) == 0) {
        red[wave][0] = vb; red[wave][1] = vc; red[wave][2] = vk; red[wave][3] = vh;
    }
    __syncthreads();
    if (tid == 0) {
        float bond    = red[0][0] + red[1][0] + red[2][0] + red[3][0];
        float clash   = red[0][1] + red[1][1] + red[2][1] + red[3][1];
        float contact = red[0][2] + red[1][2] + red[2][2] + red[3][2];
        float hb      = red[0][3] + red[1][3] + red[2][3] + red[3][3];
        float inv_nn  = 1.f / ((float)n * (float)n);
        float e = 30.f * bond / (float)(n - 1)
                + 50.f * clash / (float)npairs
                + 5.f  * contact * inv_nn
                + 4.f  * hb * inv_nn;
        out[0] = e;
    }
}

extern "C" void kernel_launch(void* const* d_in, const int* in_sizes, int n_in,
                              void* d_out, int out_size, void* d_ws, size_t ws_size,
                              hipStream_t stream) {
    const float* ca    = (const float*)d_in[0];
    const float* K     = (const float*)d_in[1];
    const int*   pairs = (const int*)d_in[2];   // int32 on device (x64 disabled)
    float* out = (float*)d_out;
    float4* partial = (float4*)d_ws;            // 512 float4 = 8 KB

    int n      = in_sizes[0] / 3;               // 4096
    int npairs = in_sizes[2] / 2;               // 500000

    energy_kernel<<<NBLK, 256, 0, stream>>>(ca, K, pairs, partial, npairs);
    finalize_kernel<<<1, 256, 0, stream>>>(partial, out, n, npairs);
}

// Round 4
// 108.989 us; speedup vs baseline: 2.1414x; 1.0190x over previous
//
#include <hip/hip_runtime.h>
#include <math.h>

#define NRES 4096
#define ROWS 8
#define COLS 2048                    // column tile per block
#define NBLK ((NRES / ROWS) * (NRES / COLS))   // 1024
#define HB_BLOCKS (NRES / 256)       // 16 blocks also do bond/hb

__device__ __forceinline__ float wave_sum(float v) {
#pragma unroll
    for (int off = 32; off > 0; off >>= 1) v += __shfl_down(v, off, 64);
    return v;
}

// sum of 4 contact terms for one K float4 vs 4 LDS columns
__device__ __forceinline__ float c4(float4 kv, float4 cx, float4 cy, float4 cz,
                                    float xi, float yi, float zi, float s) {
    float dx, dy, dz, sq, D, t;
    dx = xi - cx.x; dy = yi - cy.x; dz = zi - cz.x;
    sq = fmaf(dx, dx, fmaf(dy, dy, dz * dz));
    D  = sqrtf(sq);
    t  = fmaf(8.f, kv.x, D - 8.f);
    s  = fmaf(t, t, s);

    dx = xi - cx.y; dy = yi - cy.y; dz = zi - cz.y;
    sq = fmaf(dx, dx, fmaf(dy, dy, dz * dz));
    D  = sqrtf(sq);
    t  = fmaf(8.f, kv.y, D - 8.f);
    s  = fmaf(t, t, s);

    dx = xi - cx.z; dy = yi - cy.z; dz = zi - cz.z;
    sq = fmaf(dx, dx, fmaf(dy, dy, dz * dz));
    D  = sqrtf(sq);
    t  = fmaf(8.f, kv.z, D - 8.f);
    s  = fmaf(t, t, s);

    dx = xi - cx.w; dy = yi - cy.w; dz = zi - cz.w;
    sq = fmaf(dx, dx, fmaf(dy, dy, dz * dz));
    D  = sqrtf(sq);
    t  = fmaf(8.f, kv.w, D - 8.f);
    s  = fmaf(t, t, s);
    return s;
}

// block b: rows [ (b>>1)*8, +8 ), cols [ (b&1)*2048, +2048 )
// every block also grid-strides clash; blocks 0..15 also do bond/hb.
__global__ __launch_bounds__(256, 4) void energy_kernel(const float* __restrict__ ca,
                                                        const float* __restrict__ K,
                                                        const int* __restrict__ pairs,
                                                        float4* __restrict__ partial,
                                                        int npairs) {
    __shared__ float sx[COLS], sy[COLS], sz[COLS];   // 24 KB
    __shared__ float red[4][4];
    const int tid  = threadIdx.x;
    const int b    = blockIdx.x;
    const int tile = b & 1;
    const int row0 = (b >> 1) * ROWS;
    const int c0   = tile * COLS;

    for (int j = tid; j < COLS; j += 256) {
        int g = c0 + j;
        sx[j] = ca[3 * g + 0];
        sy[j] = ca[3 * g + 1];
        sz[j] = ca[3 * g + 2];
    }
    __syncthreads();

    // row coordinates (L1-hot global reads)
    float xi[ROWS], yi[ROWS], zi[ROWS];
#pragma unroll
    for (int r = 0; r < ROWS; ++r) {
        int g = row0 + r;
        xi[r] = ca[3 * g + 0];
        yi[r] = ca[3 * g + 1];
        zi[r] = ca[3 * g + 2];
    }

    // -------- contact: 2 column-chunks x 8 rows, pipelined in groups of 4 --------
    const float* Kb = K + (size_t)row0 * NRES + c0;
    const int j0 = tid << 2;          // chunk0 column (floats)
    const int j1 = (tid + 256) << 2;  // chunk1 column
    float contact = 0.f;

    float4 va[4], vb[4];
#pragma unroll
    for (int r = 0; r < 4; ++r) va[r] = *(const float4*)(Kb + (size_t)r * NRES + j0);
#pragma unroll
    for (int r = 0; r < 4; ++r) vb[r] = *(const float4*)(Kb + (size_t)(4 + r) * NRES + j0);

    float4 cx0 = *(const float4*)&sx[j0];
    float4 cy0 = *(const float4*)&sy[j0];
    float4 cz0 = *(const float4*)&sz[j0];

#pragma unroll
    for (int r = 0; r < 4; ++r) contact = c4(va[r], cx0, cy0, cz0, xi[r], yi[r], zi[r], contact);
#pragma unroll
    for (int r = 0; r < 4; ++r) va[r] = *(const float4*)(Kb + (size_t)r * NRES + j1);
#pragma unroll
    for (int r = 0; r < 4; ++r) contact = c4(vb[r], cx0, cy0, cz0, xi[4 + r], yi[4 + r], zi[4 + r], contact);
#pragma unroll
    for (int r = 0; r < 4; ++r) vb[r] = *(const float4*)(Kb + (size_t)(4 + r) * NRES + j1);

    float4 cx1 = *(const float4*)&sx[j1];
    float4 cy1 = *(const float4*)&sy[j1];
    float4 cz1 = *(const float4*)&sz[j1];

#pragma unroll
    for (int r = 0; r < 4; ++r) contact = c4(va[r], cx1, cy1, cz1, xi[r], yi[r], zi[r], contact);
#pragma unroll
    for (int r = 0; r < 4; ++r) contact = c4(vb[r], cx1, cy1, cz1, xi[4 + r], yi[4 + r], zi[4 + r], contact);

    // -------- clash: grid-stride, coords from global (L1/L2-hot 48 KB table) --------
    float clash = 0.f;
    for (int p = b * 256 + tid; p < npairs; p += NBLK * 256) {
        int2 pr = ((const int2*)pairs)[p];
        float dx = ca[3 * pr.x + 0] - ca[3 * pr.y + 0];
        float dy = ca[3 * pr.x + 1] - ca[3 * pr.y + 1];
        float dz = ca[3 * pr.x + 2] - ca[3 * pr.y + 2];
        float d  = sqrtf(fmaxf(fmaf(dx, dx, fmaf(dy, dy, dz * dz)), 1e-12f));
        float r  = fmaxf(3.2f - d, 0.f);
        clash = fmaf(r, r, clash);
    }

    // -------- bond + hb: blocks 0..15, residue i = b*256+tid --------
    float bond = 0.f, hb = 0.f;
    if (b < HB_BLOCKS) {
        const int i = b * 256 + tid;
        const int n = NRES;

        if (i < n - 1) {
            float dx = ca[3*(i+1)+0] - ca[3*i+0];
            float dy = ca[3*(i+1)+1] - ca[3*i+1];
            float dz = ca[3*(i+1)+2] - ca[3*i+2];
            float d  = sqrtf(fmaf(dx, dx, fmaf(dy, dy, dz * dz)));
            float t  = d - 3.8f;
            bond = t * t;
        }

        if (i < n - 2) {
            float cax = ca[3*i+0], cay = ca[3*i+1], caz = ca[3*i+2];
            float vx = ca[3*(i+1)+0] - cax, vy = ca[3*(i+1)+1] - cay, vz = ca[3*(i+1)+2] - caz;
            float inv = 1.f / (sqrtf(vx*vx + vy*vy + vz*vz) + 1e-8f);
            float ux = vx*inv, uy = vy*inv, uz = vz*inv;

            float upx, upy, upz;
            if (i == 0) { upx = ux; upy = uy; upz = uz; }
            else {
                float wx = cax - ca[3*(i-1)+0], wy = cay - ca[3*(i-1)+1], wz = caz - ca[3*(i-1)+2];
                float inv2 = 1.f / (sqrtf(wx*wx + wy*wy + wz*wz) + 1e-8f);
                upx = wx*inv2; upy = wy*inv2; upz = wz*inv2;
            }

            float vcx = 0.38f*ux,  vcy = 0.38f*uy,  vcz = 0.38f*uz;
            float vnx = -0.38f*upx, vny = -0.38f*upy, vnz = -0.38f*upz;
            float px = vcy*vnz - vcz*vny;
            float py = vcz*vnx - vcx*vnz;
            float pz = vcx*vny - vcy*vnx;
            float pn = sqrtf(px*px + py*py + pz*pz);
            if (pn > 1e-6f) {
                float ipn = 1.f / fmaxf(pn, 1e-12f);
                px *= ipn; py *= ipn; pz *= ipn;
            }
            float ox = cax + vcx + 1.24f*px;
            float oy = cay + vcy + 1.24f*py;
            float oz = caz + vcz + 1.24f*pz;

#pragma unroll
            for (int off = 2; off <= 5; ++off) {
                int jj = i + off;
                if (jj < n) {
                    float cjx = ca[3*jj+0], cjy = ca[3*jj+1], cjz = ca[3*jj+2];
                    float qx = cjx - ca[3*(jj-1)+0], qy = cjy - ca[3*(jj-1)+1], qz = cjz - ca[3*(jj-1)+2];
                    float invq = 1.f / (sqrtf(qx*qx + qy*qy + qz*qz) + 1e-8f);
                    float njx = cjx - 0.38f*qx*invq;
                    float njy = cjy - 0.38f*qy*invq;
                    float njz = cjz - 0.38f*qz*invq;
                    float ddx = ox-njx, ddy = oy-njy, ddz = oz-njz;
                    float d = sqrtf(ddx*ddx + ddy*ddy + ddz*ddz);
                    if (d > 2.5f && d < 3.5f) {
                        float z = (d - 2.95f) * (1.0f / 0.3f);
                        hb -= 0.5f * expf(-z*z);
                    }
                }
            }
        }
    }

    // -------- block reduce -> partial[b] (no atomics) --------
    float vbo = wave_sum(bond);
    float vcl = wave_sum(clash);
    float vco = wave_sum(contact);
    float vhb = wave_sum(hb);
    const int wave = tid >> 6;
    if ((tid & 63) == 0) {
        red[wave][0] = vbo; red[wave][1] = vcl; red[wave][2] = vco; red[wave][3] = vhb;
    }
    __syncthreads();
    if (tid == 0) {
        float4 o;
        o.x = red[0][0] + red[1][0] + red[2][0] + red[3][0];
        o.y = red[0][1] + red[1][1] + red[2][1] + red[3][1];
        o.z = red[0][2] + red[1][2] + red[2][2] + red[3][2];
        o.w = red[0][3] + red[1][3] + red[2][3] + red[3][3];
        partial[b] = o;
    }
}

// ---- reduce 1024 partials, apply weights ----
__global__ __launch_bounds__(256) void finalize_kernel(const float4* __restrict__ partial,
                                                       float* __restrict__ out,
                                                       int n, int npairs) {
    __shared__ float red[4][4];
    const int tid = threadIdx.x;
    float vb = 0.f, vc = 0.f, vk = 0.f, vh = 0.f;
#pragma unroll
    for (int s = 0; s < NBLK; s += 256) {
        float4 a = partial[tid + s];
        vb += a.x; vc += a.y; vk += a.z; vh += a.w;
    }
    vb = wave_sum(vb); vc = wave_sum(vc); vk = wave_sum(vk); vh = wave_sum(vh);
    const int wave = tid >> 6;
    if ((tid & 63) == 0) {
        red[wave][0] = vb; red[wave][1] = vc; red[wave][2] = vk; red[wave][3] = vh;
    }
    __syncthreads();
    if (tid == 0) {
        float bond    = red[0][0] + red[1][0] + red[2][0] + red[3][0];
        float clash   = red[0][1] + red[1][1] + red[2][1] + red[3][1];
        float contact = red[0][2] + red[1][2] + red[2][2] + red[3][2];
        float hb      = red[0][3] + red[1][3] + red[2][3] + red[3][3];
        float inv_nn  = 1.f / ((float)n * (float)n);
        out[0] = 30.f * bond / (float)(n - 1)
               + 50.f * clash / (float)npairs
               + 5.f  * contact * inv_nn
               + 4.f  * hb * inv_nn;
    }
}

extern "C" void kernel_launch(void* const* d_in, const int* in_sizes, int n_in,
                              void* d_out, int out_size, void* d_ws, size_t ws_size,
                              hipStream_t stream) {
    const float* ca    = (const float*)d_in[0];
    const float* K     = (const float*)d_in[1];
    const int*   pairs = (const int*)d_in[2];   // int32 on device (x64 disabled)
    float* out = (float*)d_out;
    float4* partial = (float4*)d_ws;            // 1024 float4 = 16 KB

    int n      = in_sizes[0] / 3;               // 4096
    int npairs = in_sizes[2] / 2;               // 500000

    energy_kernel<<<NBLK, 256, 0, stream>>>(ca, K, pairs, partial, npairs);
    finalize_kernel<<<1, 256, 0, stream>>>(partial, out, n, npairs);
}

// Round 5
// 101.348 us; speedup vs baseline: 2.3028x; 1.0754x over previous
//
#include <hip/hip_runtime.h>
#include <math.h>

#define NRES   4096
#define GRID   768                 // 3 blocks/CU exactly (48KB LDS cap)
#define TROWS  4
#define NTILES (NRES / TROWS)      // 1024 row-tiles; blocks 0..255 take 2 tiles
#define HB_BLOCKS (NRES / 256)     // 16

__device__ __forceinline__ float wave_sum(float v) {
#pragma unroll
    for (int off = 32; off > 0; off >>= 1) v += __shfl_down(v, off, 64);
    return v;
}

// raw v_sqrt_f32 (≈1 ulp), skips libm's IEEE fixup sequence
__device__ __forceinline__ float fsqrt(float x) { return __builtin_amdgcn_sqrtf(x); }

// 4 contact terms: one K float4 vs 4 LDS columns
__device__ __forceinline__ float c4(float4 kv, float4 cx, float4 cy, float4 cz,
                                    float xi, float yi, float zi, float s) {
    float dx, dy, dz, D, t;
    dx = xi - cx.x; dy = yi - cy.x; dz = zi - cz.x;
    D  = fsqrt(fmaf(dx, dx, fmaf(dy, dy, dz * dz)));
    t  = fmaf(8.f, kv.x, D - 8.f);   // D - 8(1-k)
    s  = fmaf(t, t, s);

    dx = xi - cx.y; dy = yi - cy.y; dz = zi - cz.y;
    D  = fsqrt(fmaf(dx, dx, fmaf(dy, dy, dz * dz)));
    t  = fmaf(8.f, kv.y, D - 8.f);
    s  = fmaf(t, t, s);

    dx = xi - cx.z; dy = yi - cy.z; dz = zi - cz.z;
    D  = fsqrt(fmaf(dx, dx, fmaf(dy, dy, dz * dz)));
    t  = fmaf(8.f, kv.z, D - 8.f);
    s  = fmaf(t, t, s);

    dx = xi - cx.w; dy = yi - cy.w; dz = zi - cz.w;
    D  = fsqrt(fmaf(dx, dx, fmaf(dy, dy, dz * dz)));
    t  = fmaf(8.f, kv.w, D - 8.f);
    s  = fmaf(t, t, s);
    return s;
}

// All blocks uniform: stage full ca table in LDS; contact over grid-strided
// 4-row tiles (K streamed, pipelined); clash grid-stride from LDS; blocks
// 0..15 also do bond/hb. Partials -> d_ws, no atomics.
__global__ __launch_bounds__(256, 3) void energy_kernel(const float* __restrict__ ca,
                                                        const float* __restrict__ K,
                                                        const int* __restrict__ pairs,
                                                        float4* __restrict__ partial,
                                                        int npairs) {
    __shared__ float sx[NRES], sy[NRES], sz[NRES];   // 48 KB
    __shared__ float red[4][4];
    const int tid = threadIdx.x;
    const int b   = blockIdx.x;

    for (int j = tid; j < NRES; j += 256) {
        sx[j] = ca[3 * j + 0];
        sy[j] = ca[3 * j + 1];
        sz[j] = ca[3 * j + 2];
    }
    __syncthreads();

    // ---------------- contact: grid-stride over 4-row tiles ----------------
    float contact = 0.f;
    for (int t = b; t < NTILES; t += GRID) {
        const int rbase = t * TROWS;
        float xi[TROWS], yi[TROWS], zi[TROWS];
#pragma unroll
        for (int r = 0; r < TROWS; ++r) {
            xi[r] = sx[rbase + r]; yi[r] = sy[rbase + r]; zi[r] = sz[rbase + r];
        }

        const float* Kt = K + (size_t)rbase * NRES;
        const int j0 = tid << 2;
        float4 va[TROWS], vb[TROWS];
#pragma unroll
        for (int r = 0; r < TROWS; ++r)
            va[r] = *(const float4*)(Kt + (size_t)r * NRES + j0);

#pragma unroll
        for (int c = 0; c < 4; ++c) {               // 4 column chunks of 1024
            const int jc = j0 + (c << 10);
            float4* cur = (c & 1) ? vb : va;
            float4* nxt = (c & 1) ? va : vb;
            if (c < 3) {
                const int jn = j0 + ((c + 1) << 10);
#pragma unroll
                for (int r = 0; r < TROWS; ++r)
                    nxt[r] = *(const float4*)(Kt + (size_t)r * NRES + jn);
            }
            const float4 cx = *(const float4*)&sx[jc];
            const float4 cy = *(const float4*)&sy[jc];
            const float4 cz = *(const float4*)&sz[jc];
#pragma unroll
            for (int r = 0; r < TROWS; ++r)
                contact = c4(cur[r], cx, cy, cz, xi[r], yi[r], zi[r], contact);
        }
    }

    // ---------------- clash: grid-stride, gathers from LDS ----------------
    float clash = 0.f;
    for (int p = b * 256 + tid; p < npairs; p += GRID * 256) {
        int2 pr = ((const int2*)pairs)[p];
        float dx = sx[pr.x] - sx[pr.y];
        float dy = sy[pr.x] - sy[pr.y];
        float dz = sz[pr.x] - sz[pr.y];
        float d  = fsqrt(fmaxf(fmaf(dx, dx, fmaf(dy, dy, dz * dz)), 1e-12f));
        float r  = fmaxf(3.2f - d, 0.f);
        clash = fmaf(r, r, clash);
    }

    // ---------------- bond + hb: blocks 0..15, from LDS ----------------
    float bond = 0.f, hb = 0.f;
    if (b < HB_BLOCKS) {
        const int i = b * 256 + tid;
        const int n = NRES;

        if (i < n - 1) {
            float dx = sx[i+1]-sx[i], dy = sy[i+1]-sy[i], dz = sz[i+1]-sz[i];
            float d  = sqrtf(fmaf(dx, dx, fmaf(dy, dy, dz * dz)));
            float t  = d - 3.8f;
            bond = t * t;
        }

        if (i < n - 2) {
            float cax = sx[i], cay = sy[i], caz = sz[i];
            float vx = sx[i+1]-cax, vy = sy[i+1]-cay, vz = sz[i+1]-caz;
            float inv = 1.f / (sqrtf(vx*vx + vy*vy + vz*vz) + 1e-8f);
            float ux = vx*inv, uy = vy*inv, uz = vz*inv;

            float upx, upy, upz;
            if (i == 0) { upx = ux; upy = uy; upz = uz; }
            else {
                float wx = cax-sx[i-1], wy = cay-sy[i-1], wz = caz-sz[i-1];
                float inv2 = 1.f / (sqrtf(wx*wx + wy*wy + wz*wz) + 1e-8f);
                upx = wx*inv2; upy = wy*inv2; upz = wz*inv2;
            }

            float vcx = 0.38f*ux,  vcy = 0.38f*uy,  vcz = 0.38f*uz;
            float vnx = -0.38f*upx, vny = -0.38f*upy, vnz = -0.38f*upz;
            float px = vcy*vnz - vcz*vny;
            float py = vcz*vnx - vcx*vnz;
            float pz = vcx*vny - vcy*vnx;
            float pn = sqrtf(px*px + py*py + pz*pz);
            if (pn > 1e-6f) {
                float ipn = 1.f / fmaxf(pn, 1e-12f);
                px *= ipn; py *= ipn; pz *= ipn;
            }
            float ox = cax + vcx + 1.24f*px;
            float oy = cay + vcy + 1.24f*py;
            float oz = caz + vcz + 1.24f*pz;

#pragma unroll
            for (int off = 2; off <= 5; ++off) {
                int jj = i + off;
                if (jj < n) {
                    float cjx = sx[jj], cjy = sy[jj], cjz = sz[jj];
                    float qx = cjx-sx[jj-1], qy = cjy-sy[jj-1], qz = cjz-sz[jj-1];
                    float invq = 1.f / (sqrtf(qx*qx + qy*qy + qz*qz) + 1e-8f);
                    float njx = cjx - 0.38f*qx*invq;
                    float njy = cjy - 0.38f*qy*invq;
                    float njz = cjz - 0.38f*qz*invq;
                    float ddx = ox-njx, ddy = oy-njy, ddz = oz-njz;
                    float d = sqrtf(ddx*ddx + ddy*ddy + ddz*ddz);
                    if (d > 2.5f && d < 3.5f) {
                        float z = (d - 2.95f) * (1.0f / 0.3f);
                        hb -= 0.5f * expf(-z*z);
                    }
                }
            }
        }
    }

    // ---------------- block reduce -> partial[b] ----------------
    float vbo = wave_sum(bond);
    float vcl = wave_sum(clash);
    float vco = wave_sum(contact);
    float vhb = wave_sum(hb);
    const int wave = tid >> 6;
    if ((tid & 63) == 0) {
        red[wave][0] = vbo; red[wave][1] = vcl; red[wave][2] = vco; red[wave][3] = vhb;
    }
    __syncthreads();
    if (tid == 0) {
        float4 o;
        o.x = red[0][0] + red[1][0] + red[2][0] + red[3][0];
        o.y = red[0][1] + red[1][1] + red[2][1] + red[3][1];
        o.z = red[0][2] + red[1][2] + red[2][2] + red[3][2];
        o.w = red[0][3] + red[1][3] + red[2][3] + red[3][3];
        partial[b] = o;
    }
}

// ---- reduce GRID partials, apply weights ----
__global__ __launch_bounds__(256) void finalize_kernel(const float4* __restrict__ partial,
                                                       float* __restrict__ out,
                                                       int n, int npairs) {
    __shared__ float red[4][4];
    const int tid = threadIdx.x;
    float vb = 0.f, vc = 0.f, vk = 0.f, vh = 0.f;
#pragma unroll
    for (int s = 0; s < GRID; s += 256) {
        float4 a = partial[tid + s];
        vb += a.x; vc += a.y; vk += a.z; vh += a.w;
    }
    vb = wave_sum(vb); vc = wave_sum(vc); vk = wave_sum(vk); vh = wave_sum(vh);
    const int wave = tid >> 6;
    if ((tid & 63) == 0) {
        red[wave][0] = vb; red[wave][1] = vc; red[wave][2] = vk; red[wave][3] = vh;
    }
    __syncthreads();
    if (tid == 0) {
        float bond    = red[0][0] + red[1][0] + red[2][0] + red[3][0];
        float clash   = red[0][1] + red[1][1] + red[2][1] + red[3][1];
        float contact = red[0][2] + red[1][2] + red[2][2] + red[3][2];
        float hb      = red[0][3] + red[1][3] + red[2][3] + red[3][3];
        float inv_nn  = 1.f / ((float)n * (float)n);
        out[0] = 30.f * bond / (float)(n - 1)
               + 50.f * clash / (float)npairs
               + 5.f  * contact * inv_nn
               + 4.f  * hb * inv_nn;
    }
}

extern "C" void kernel_launch(void* const* d_in, const int* in_sizes, int n_in,
                              void* d_out, int out_size, void* d_ws, size_t ws_size,
                              hipStream_t stream) {
    const float* ca    = (const float*)d_in[0];
    const float* K     = (const float*)d_in[1];
    const int*   pairs = (const int*)d_in[2];   // int32 on device (x64 disabled)
    float* out = (float*)d_out;
    float4* partial = (float4*)d_ws;            // GRID float4 = 12 KB

    int n      = in_sizes[0] / 3;               // 4096
    int npairs = in_sizes[2] / 2;               // 500000

    energy_kernel<<<GRID, 256, 0, stream>>>(ca, K, pairs, partial, npairs);
    finalize_kernel<<<1, 256, 0, stream>>>(partial, out, n, npairs);
}